// Round 10
// baseline (160.324 us; speedup 1.0000x reference)
//
#include <hip/hip_runtime.h>

typedef unsigned short u16;
typedef __attribute__((ext_vector_type(8))) short bf16x8;
typedef __attribute__((ext_vector_type(4))) float f32x4;
typedef __attribute__((ext_vector_type(16))) float f32x16;
typedef __attribute__((ext_vector_type(2))) int i32x2;

#define MFMA16(A, B, C) __builtin_amdgcn_mfma_f32_16x16x32_bf16((A), (B), (C), 0, 0, 0)
#define MFMA32(A, B, C) __builtin_amdgcn_mfma_f32_32x32x16_bf16((A), (B), (C), 0, 0, 0)

// constants
#define BB 4
#define CC 256
#define HW 4096
#define NH 4
#define HD 64

// 0.125 (d^-0.5) * log2(e): softmax done in exp2 domain
#define QSCALE 0.18033688f

__device__ __forceinline__ u16 f2bf(float f) {
  unsigned int u = __builtin_bit_cast(unsigned int, f);
  u += 0x7fffu + ((u >> 16) & 1u);   // RNE
  return (u16)(u >> 16);
}

__device__ __forceinline__ unsigned cvtpk(float a, float b) {
  unsigned r;
  asm("v_cvt_pk_bf16_f32 %0, %1, %2" : "=v"(r) : "v"(a), "v"(b));
  return r;
}

// ---------------- Kernel 0: weights fp32 -> bf16 (once) ----------------
__global__ __launch_bounds__(256) void w2bf_kernel(const float* __restrict__ qw,
                                                   const float* __restrict__ pw,
                                                   u16* __restrict__ wbf) {
  int idx = (blockIdx.x * 256 + threadIdx.x) * 4;
  const int NQ = 768 * 256;
  const float* src = (idx < NQ) ? (qw + idx) : (pw + (idx - NQ));
  float4 v = *(const float4*)src;
  union { u16 u[4]; uint2 w; } pk;
  pk.u[0] = f2bf(v.x); pk.u[1] = f2bf(v.y);
  pk.u[2] = f2bf(v.z); pk.u[3] = f2bf(v.w);
  *(uint2*)(wbf + idx) = pk.w;
}

// ---------------- Kernel 1a: GroupNorm partial sums (256 blocks) ----------------
__global__ __launch_bounds__(256) void gn_partial_kernel(const float* __restrict__ x,
                                                         float* __restrict__ partial) {
  const float4* p = (const float4*)(x + (size_t)blockIdx.x * 16384);
  float s = 0.f, ss = 0.f;
  for (int i = threadIdx.x; i < 4096; i += 256) {
    float4 v = p[i];
    s += (v.x + v.y) + (v.z + v.w);
    ss += (v.x * v.x + v.y * v.y) + (v.z * v.z + v.w * v.w);
  }
#pragma unroll
  for (int msk = 32; msk; msk >>= 1) {
    s += __shfl_xor(s, msk);
    ss += __shfl_xor(ss, msk);
  }
  __shared__ float red[2][4];
  int wave = threadIdx.x >> 6;
  if ((threadIdx.x & 63) == 0) { red[0][wave] = s; red[1][wave] = ss; }
  __syncthreads();
  if (threadIdx.x == 0) {
    partial[blockIdx.x] = red[0][0] + red[0][1] + red[0][2] + red[0][3];
    partial[256 + blockIdx.x] = red[1][0] + red[1][1] + red[1][2] + red[1][3];
  }
}

// ---------------- Kernel 1b: finalize stats (1 block) ----------------
__global__ __launch_bounds__(64) void gn_final_kernel(const float* __restrict__ partial,
                                                      float* __restrict__ stats) {
  int bg = threadIdx.x;
  if (bg < 32) {
    float S = 0.f, SS = 0.f;
#pragma unroll
    for (int sp = 0; sp < 8; ++sp) {
      S += partial[bg * 8 + sp];
      SS += partial[256 + bg * 8 + sp];
    }
    const float invN = 1.0f / 131072.0f;
    float mean = S * invN;
    float var = SS * invN - mean * mean;
    stats[bg] = mean;
    stats[32 + bg] = rsqrtf(var + 1e-5f);
  }
}

// ---------------- Kernel 2: normalize + transpose -> h_t[b][s][c] (bf16) ----------------
__global__ __launch_bounds__(256) void norm_t_kernel(const float* __restrict__ x,
                                                     const float* __restrict__ nw,
                                                     const float* __restrict__ nb,
                                                     const float* __restrict__ stats,
                                                     u16* __restrict__ h_t) {
  int b = blockIdx.y;
  int s = blockIdx.x * 64 + (threadIdx.x & 63);
  int w = threadIdx.x >> 6;
  const float* xb = x + (size_t)b * CC * HW;
  u16* hb = h_t + ((size_t)b * HW + s) * CC;
#pragma unroll
  for (int cc = 0; cc < 8; ++cc) {
    int c0 = w * 64 + cc * 8;
    union { u16 u[8]; uint4 v; } pk;
#pragma unroll
    for (int j = 0; j < 8; ++j) {
      int c = c0 + j;
      int g = c >> 5;
      float mean = stats[b * 8 + g];
      float rstd = stats[32 + b * 8 + g];
      float a = nw[c] * rstd;
      float bb2 = nb[c] - mean * a;
      float vv = xb[(size_t)c * HW + s];
      pk.u[j] = f2bf(vv * a + bb2);
    }
    *(uint4*)(hb + c0) = pk.v;
  }
}

// ---------------- Kernel 3: qk GEMM -> q_t[b][h][s][c] ; K in FRAGMENT-MAJOR ----
// K layout: kf[bh][jb32][kc][lane][8] with lane = hi*32 + ql:
//   element = K[jb32*32 + ql][kc*16 + hi*8 + j]
__global__ __launch_bounds__(256) void gemm_qk_kernel(const u16* __restrict__ h_t,
                                                      const u16* __restrict__ wbf,
                                                      const float* __restrict__ qb,
                                                      u16* __restrict__ q_t,
                                                      u16* __restrict__ k_f) {
  int b = blockIdx.z;
  int lane = threadIdx.x & 63, wave = threadIdx.x >> 6;
  int lr = lane & 15, lg = lane >> 4;
  int m0 = blockIdx.x * 128 + (wave >> 1) * 64;  // s
  int n0 = blockIdx.y * 128 + (wave & 1) * 64;   // o (0..512)
  const u16* hb = h_t + (size_t)b * HW * CC;
  f32x4 acc[4][4] = {};
  for (int kc = 0; kc < 8; ++kc) {
    int ko = kc * 32 + lg * 8;
    bf16x8 af[4], bfr[4];
#pragma unroll
    for (int mi = 0; mi < 4; ++mi)
      af[mi] = *(const bf16x8*)(hb + (size_t)(m0 + mi * 16 + lr) * CC + ko);
#pragma unroll
    for (int ni = 0; ni < 4; ++ni)
      bfr[ni] = *(const bf16x8*)(wbf + (size_t)(n0 + ni * 16 + lr) * CC + ko);
#pragma unroll
    for (int mi = 0; mi < 4; ++mi)
#pragma unroll
      for (int ni = 0; ni < 4; ++ni)
        acc[mi][ni] = MFMA16(af[mi], bfr[ni], acc[mi][ni]);
  }
  bool isq = (blockIdx.y < 2);
  if (isq) {
#pragma unroll
    for (int ni = 0; ni < 4; ++ni) {
      int o = n0 + ni * 16 + lr;
      float bias = qb[o];
      u16* dp = q_t + (((size_t)b * NH + (o >> 6)) * HW) * HD + (o & 63);
#pragma unroll
      for (int mi = 0; mi < 4; ++mi)
#pragma unroll
        for (int r = 0; r < 4; ++r) {
          int s = m0 + mi * 16 + lg * 4 + r;
          dp[(size_t)s * HD] = f2bf((acc[mi][ni][r] + bias) * QSCALE);
        }
    }
  } else {
#pragma unroll
    for (int ni = 0; ni < 4; ++ni) {
      int o = n0 + ni * 16 + lr;
      int oc = o - 256;
      int h = oc >> 6, c = oc & 63;
      int kc = c >> 4, hi2 = (c >> 3) & 1, j = c & 7;
      float bias = qb[o];
      u16* base = k_f + (size_t)(b * NH + h) * HW * HD;
#pragma unroll
      for (int mi = 0; mi < 4; ++mi)
#pragma unroll
        for (int r = 0; r < 4; ++r) {
          int s = m0 + mi * 16 + lg * 4 + r;
          int jb32 = s >> 5, ql2 = s & 31;
          base[((size_t)(jb32 * 4 + kc) * 64 + hi2 * 32 + ql2) * 8 + j] =
              f2bf(acc[mi][ni][r] + bias);
        }
    }
  }
}

// ---------------- Kernel 4: v GEMM -> V in FRAGMENT-MAJOR ----------------
// V layout: vf[bh][jb64][half][kc][lane][8] with lane = hi*32 + ql:
//   element = V[half*32 + ql][jb64*64 + kc*16 + hi*8 + j]   (V = [c][kv])
__global__ __launch_bounds__(256) void gemm_v_kernel(const u16* __restrict__ h_t,
                                                     const u16* __restrict__ wbf,
                                                     const float* __restrict__ qb,
                                                     u16* __restrict__ v_f) {
  int b = blockIdx.z;
  int lane = threadIdx.x & 63, wave = threadIdx.x >> 6;
  int lr = lane & 15, lg = lane >> 4;
  int m0 = blockIdx.y * 128 + (wave >> 1) * 64;  // o (0..255) = channel dim
  int n0 = blockIdx.x * 128 + (wave & 1) * 64;   // s = kv dim
  const u16* hb = h_t + (size_t)b * HW * CC;
  f32x4 acc[4][4] = {};
  for (int kc = 0; kc < 8; ++kc) {
    int ko = kc * 32 + lg * 8;
    bf16x8 af[4], bfr[4];
#pragma unroll
    for (int mi = 0; mi < 4; ++mi)
      af[mi] = *(const bf16x8*)(wbf + (size_t)(512 + m0 + mi * 16 + lr) * CC + ko);
#pragma unroll
    for (int ni = 0; ni < 4; ++ni)
      bfr[ni] = *(const bf16x8*)(hb + (size_t)(n0 + ni * 16 + lr) * CC + ko);
#pragma unroll
    for (int mi = 0; mi < 4; ++mi)
#pragma unroll
      for (int ni = 0; ni < 4; ++ni)
        acc[mi][ni] = MFMA16(af[mi], bfr[ni], acc[mi][ni]);
  }
#pragma unroll
  for (int mi = 0; mi < 4; ++mi)
#pragma unroll
    for (int r = 0; r < 4; ++r) {
      int o = m0 + mi * 16 + lg * 4 + r;
      int h = o >> 6, c = o & 63;
      int half = c >> 5, qlc = c & 31;
      float bias = qb[512 + o];
      u16* base = v_f + (size_t)(b * NH + h) * HW * HD;
#pragma unroll
      for (int ni = 0; ni < 4; ++ni) {
        int s = n0 + ni * 16 + lr;
        int jb64 = s >> 6, w = s & 63;
        int kc = w >> 4, hi2 = (w >> 3) & 1, j = w & 7;
        base[((size_t)((jb64 * 2 + half) * 4 + kc) * 64 + hi2 * 32 + qlc) * 8 + j] =
            f2bf(acc[mi][ni][r] + bias);
      }
    }
}

// ---------------- Kernel 5: flash attention, LDS-FREE via fragment-major K/V ----
// 4 independent waves/block, 32 q-rows/wave. K/V fragments load as fully
// coalesced 1KB global_load_dwordx4 (base + lane*16B) from the fragment-major
// buffers. No LDS, no barriers, no bank conflicts. Fixed-reference softmax.
// K single-buffered in regs (reload right after QK); V loaded at iter top.
__global__ __launch_bounds__(256) void attn_kernel(const u16* __restrict__ q_t,
                                                   const u16* __restrict__ k_f,
                                                   const u16* __restrict__ v_f,
                                                   u16* __restrict__ o_t) {
  int bh = blockIdx.y;
  int tid = threadIdx.x;
  int wave = tid >> 6, lane = tid & 63;
  int ql = lane & 31, hi = lane >> 5;
  int q0w = blockIdx.x * 128 + wave * 32;
  const u16* qp = q_t + (size_t)bh * HW * HD;
  const u16* kfb = k_f + (size_t)bh * HW * HD + lane * 8;  // + (jb32*4+kc)*512
  const u16* vfb = v_f + (size_t)bh * HW * HD + lane * 8;  // + ((jb64*2+half)*4+kc)*512

  // Q B-fragments (B[k=c][n=q])
  bf16x8 qf[4];
#pragma unroll
  for (int kc = 0; kc < 4; ++kc)
    qf[kc] = *(const bf16x8*)(qp + (size_t)(q0w + ql) * HD + kc * 16 + hi * 8);

  float l_run = 0.f;
  f32x16 of0 = {}, of1 = {};
  bf16x8 kfr[8], vfr[8];

  // prologue: K(0) fragments (jb32 = 0,1)
#pragma unroll
  for (int kc = 0; kc < 4; ++kc) {
    kfr[kc] = *(const bf16x8*)(kfb + (size_t)kc * 512);
    kfr[4 + kc] = *(const bf16x8*)(kfb + (size_t)(4 + kc) * 512);
  }

#pragma unroll 1
  for (int it = 0; it < 64; ++it) {
    // V(it) fragment loads — consumed at PV after exp2+pack (~250 cyc slack)
    const u16* vb = vfb + (size_t)it * 8 * 512;
#pragma unroll
    for (int kc = 0; kc < 4; ++kc) {
      vfr[kc] = *(const bf16x8*)(vb + (size_t)kc * 512);          // half 0
      vfr[4 + kc] = *(const bf16x8*)(vb + (size_t)(4 + kc) * 512);  // half 1
    }

    // QK(it): S[kv][q] = K·Q  (scale+log2e folded into q)
    f32x16 s0 = {}, s1 = {};
    __builtin_amdgcn_s_setprio(1);
#pragma unroll
    for (int kc = 0; kc < 4; ++kc) {
      s0 = MFMA32(kfr[kc], qf[kc], s0);
      s1 = MFMA32(kfr[4 + kc], qf[kc], s1);
    }
    __builtin_amdgcn_s_setprio(0);

    // K(it+1) fragment loads (WAR on kfr is safe: MFMA read at issue)
    if (it < 63) {
      const u16* kb = kfb + (size_t)(it + 1) * 8 * 512;
#pragma unroll
      for (int kc = 0; kc < 4; ++kc) {
        kfr[kc] = *(const bf16x8*)(kb + (size_t)kc * 512);
        kfr[4 + kc] = *(const bf16x8*)(kb + (size_t)(4 + kc) * 512);
      }
    }

    // P = exp2(S) directly — fixed reference (no max tracking)
#pragma unroll
    for (int i = 0; i < 16; ++i) {
      s0[i] = __builtin_amdgcn_exp2f(s0[i]);
      s1[i] = __builtin_amdgcn_exp2f(s1[i]);
    }

    // pf(it) = P -> bf16 B-fragments via cvt_pk + permlane32_swap
    bf16x8 pf[4];
#pragma unroll
    for (int kc = 0; kc < 4; ++kc) {
      const f32x16 pv = (kc < 2) ? s0 : s1;
      const int b8 = (kc & 1) * 8;
      unsigned A0 = cvtpk(pv[b8 + 0], pv[b8 + 1]);
      unsigned A1 = cvtpk(pv[b8 + 2], pv[b8 + 3]);
      unsigned B0 = cvtpk(pv[b8 + 4], pv[b8 + 5]);
      unsigned B1 = cvtpk(pv[b8 + 6], pv[b8 + 7]);
      i32x2 r0 = __builtin_amdgcn_permlane32_swap((int)A0, (int)B0, false, false);
      i32x2 r1 = __builtin_amdgcn_permlane32_swap((int)A1, (int)B1, false, false);
      union { unsigned w[4]; bf16x8 v8; } u;
      u.w[0] = (unsigned)r0[0]; u.w[1] = (unsigned)r1[0];
      u.w[2] = (unsigned)r0[1]; u.w[3] = (unsigned)r1[1];
      pf[kc] = u.v8;
    }

    // PV(it): O^T[c][q] += V^T · P^T
    __builtin_amdgcn_s_setprio(1);
#pragma unroll
    for (int kc = 0; kc < 4; ++kc) {
      of0 = MFMA32(vfr[kc], pf[kc], of0);
      of1 = MFMA32(vfr[4 + kc], pf[kc], of1);
    }
    __builtin_amdgcn_s_setprio(0);

    // l-sum AFTER PV issue (off the critical path)
    float t8[8];
#pragma unroll
    for (int i = 0; i < 8; ++i)
      t8[i] = (s0[i] + s0[i + 8]) + (s1[i] + s1[i + 8]);
    float t4a = t8[0] + t8[4], t4b = t8[1] + t8[5];
    float t4c = t8[2] + t8[6], t4d = t8[3] + t8[7];
    l_run += (t4a + t4b) + (t4c + t4d);
  }

  // epilogue: out[c][q] / l -> o_t[b][s=q][hh*64 + c]
  float l_tot = l_run + __shfl_xor(l_run, 32);
  float inv_l = 1.0f / l_tot;
  int bb = bh >> 2, hh = bh & 3;
  u16* orow = o_t + ((size_t)bb * HW + q0w + ql) * CC + hh * 64;
#pragma unroll
  for (int cb = 0; cb < 2; ++cb) {
    const f32x16 o = cb ? of1 : of0;
#pragma unroll
    for (int t = 0; t < 4; ++t) {
      int c0 = cb * 32 + t * 8 + hi * 4;
      union { u16 u[4]; uint2 w; } pk;
#pragma unroll
      for (int r = 0; r < 4; ++r) pk.u[r] = f2bf(o[t * 4 + r] * inv_l);
      *(uint2*)(orow + c0) = pk.w;
    }
  }
}

// ---------------- Kernel 6: proj GEMM + bias + residual (fp32 out) ----------------
__global__ __launch_bounds__(256) void proj_kernel(const u16* __restrict__ o_t,
                                                   const u16* __restrict__ wbf,
                                                   const float* __restrict__ pb,
                                                   const float* __restrict__ x,
                                                   float* __restrict__ out) {
  int b = blockIdx.z;
  int lane = threadIdx.x & 63, wave = threadIdx.x >> 6;
  int lr = lane & 15, lg = lane >> 4;
  int m0 = blockIdx.x * 128 + (wave >> 1) * 64;  // s
  int n0 = blockIdx.y * 128 + (wave & 1) * 64;   // o (0..255)
  const u16* ob = o_t + (size_t)b * HW * CC;
  const u16* pwbf = wbf + (size_t)768 * CC;
  f32x4 acc[4][4] = {};
  for (int kc = 0; kc < 8; ++kc) {
    int ko = kc * 32 + lg * 8;
    bf16x8 af[4], bfr[4];
#pragma unroll
    for (int mi = 0; mi < 4; ++mi)
      af[mi] = *(const bf16x8*)(ob + (size_t)(m0 + mi * 16 + lr) * CC + ko);
#pragma unroll
    for (int ni = 0; ni < 4; ++ni)
      bfr[ni] = *(const bf16x8*)(pwbf + (size_t)(n0 + ni * 16 + lr) * CC + ko);
#pragma unroll
    for (int mi = 0; mi < 4; ++mi)
#pragma unroll
      for (int ni = 0; ni < 4; ++ni)
        acc[mi][ni] = MFMA16(af[mi], bfr[ni], acc[mi][ni]);
  }
#pragma unroll
  for (int ni = 0; ni < 4; ++ni) {
    int o = n0 + ni * 16 + lr;
    float bias = pb[o];
    const float* xp = x + ((size_t)b * CC + o) * HW;
    float* op = out + ((size_t)b * CC + o) * HW;
#pragma unroll
    for (int mi = 0; mi < 4; ++mi) {
      int sb = m0 + mi * 16 + lg * 4;
      float4 xv = *(const float4*)(xp + sb);
      float4 res;
      res.x = acc[mi][ni][0] + bias + xv.x;
      res.y = acc[mi][ni][1] + bias + xv.y;
      res.z = acc[mi][ni][2] + bias + xv.z;
      res.w = acc[mi][ni][3] + bias + xv.w;
      *(float4*)(op + sb) = res;
    }
  }
}

extern "C" void kernel_launch(void* const* d_in, const int* in_sizes, int n_in,
                              void* d_out, int out_size, void* d_ws, size_t ws_size,
                              hipStream_t stream) {
  const float* x = (const float*)d_in[0];
  const float* nw = (const float*)d_in[1];
  const float* nb = (const float*)d_in[2];
  const float* qw = (const float*)d_in[3];
  const float* qb = (const float*)d_in[4];
  const float* pw = (const float*)d_in[5];
  const float* pb = (const float*)d_in[6];
  float* out = (float*)d_out;

  // workspace layout (o_t aliases h_t: h_t dead after gemm_v)
  float* stats = (float*)d_ws;                       // 64 floats
  float* partial = stats + 64;                       // 512 floats
  u16* h_t = (u16*)((char*)d_ws + 4096);             // [B][HW][C]      8 MB
  u16* q_t = h_t + (size_t)BB * HW * CC;             // [B][NH][HW][HD] 8 MB
  u16* k_f = q_t + (size_t)BB * HW * CC;             // fragment-major  8 MB
  u16* v_f = k_f + (size_t)BB * HW * CC;             // fragment-major  8 MB
  u16* wbf = v_f + (size_t)BB * HW * CC;             // (768+256)*256   512 KB
  u16* o_t = h_t;                                    // reuse

  gn_partial_kernel<<<256, 256, 0, stream>>>(x, partial);
  gn_final_kernel<<<1, 64, 0, stream>>>(partial, stats);
  w2bf_kernel<<<256, 256, 0, stream>>>(qw, pw, wbf);
  norm_t_kernel<<<dim3(HW / 64, BB), 256, 0, stream>>>(x, nw, nb, stats, h_t);
  gemm_qk_kernel<<<dim3(HW / 128, 4, BB), 256, 0, stream>>>(h_t, wbf, qb, q_t, k_f);
  gemm_v_kernel<<<dim3(HW / 128, 2, BB), 256, 0, stream>>>(h_t, wbf, qb, v_f);
  attn_kernel<<<dim3(HW / 128, BB * NH), 256, 0, stream>>>(q_t, k_f, v_f, o_t);
  proj_kernel<<<dim3(HW / 128, 2, BB), 256, 0, stream>>>(o_t, wbf, pb, x, out);
}

// Round 11
// 153.962 us; speedup vs baseline: 1.0413x; 1.0413x over previous
//
#include <hip/hip_runtime.h>

typedef unsigned short u16;
typedef __attribute__((ext_vector_type(8))) short bf16x8;
typedef __attribute__((ext_vector_type(4))) float f32x4;
typedef __attribute__((ext_vector_type(16))) float f32x16;
typedef __attribute__((ext_vector_type(2))) int i32x2;

#define MFMA16(A, B, C) __builtin_amdgcn_mfma_f32_16x16x32_bf16((A), (B), (C), 0, 0, 0)
#define MFMA32(A, B, C) __builtin_amdgcn_mfma_f32_32x32x16_bf16((A), (B), (C), 0, 0, 0)

// constants
#define BB 4
#define CC 256
#define HW 4096
#define NH 4
#define HD 64

// 0.125 (d^-0.5) * log2(e): softmax done in exp2 domain
#define QSCALE 0.18033688f

__device__ __forceinline__ u16 f2bf(float f) {
  unsigned int u = __builtin_bit_cast(unsigned int, f);
  u += 0x7fffu + ((u >> 16) & 1u);   // RNE
  return (u16)(u >> 16);
}

__device__ __forceinline__ unsigned cvtpk(float a, float b) {
  unsigned r;
  asm("v_cvt_pk_bf16_f32 %0, %1, %2" : "=v"(r) : "v"(a), "v"(b));
  return r;
}

// ---------------- Kernel 0: weights fp32 -> bf16 (once) ----------------
__global__ __launch_bounds__(256) void w2bf_kernel(const float* __restrict__ qw,
                                                   const float* __restrict__ pw,
                                                   u16* __restrict__ wbf) {
  int idx = (blockIdx.x * 256 + threadIdx.x) * 4;
  const int NQ = 768 * 256;
  const float* src = (idx < NQ) ? (qw + idx) : (pw + (idx - NQ));
  float4 v = *(const float4*)src;
  union { u16 u[4]; uint2 w; } pk;
  pk.u[0] = f2bf(v.x); pk.u[1] = f2bf(v.y);
  pk.u[2] = f2bf(v.z); pk.u[3] = f2bf(v.w);
  *(uint2*)(wbf + idx) = pk.w;
}

// ---------------- Kernel 1a: GroupNorm partial sums (256 blocks) ----------------
__global__ __launch_bounds__(256) void gn_partial_kernel(const float* __restrict__ x,
                                                         float* __restrict__ partial) {
  const float4* p = (const float4*)(x + (size_t)blockIdx.x * 16384);
  float s = 0.f, ss = 0.f;
  for (int i = threadIdx.x; i < 4096; i += 256) {
    float4 v = p[i];
    s += (v.x + v.y) + (v.z + v.w);
    ss += (v.x * v.x + v.y * v.y) + (v.z * v.z + v.w * v.w);
  }
#pragma unroll
  for (int msk = 32; msk; msk >>= 1) {
    s += __shfl_xor(s, msk);
    ss += __shfl_xor(ss, msk);
  }
  __shared__ float red[2][4];
  int wave = threadIdx.x >> 6;
  if ((threadIdx.x & 63) == 0) { red[0][wave] = s; red[1][wave] = ss; }
  __syncthreads();
  if (threadIdx.x == 0) {
    partial[blockIdx.x] = red[0][0] + red[0][1] + red[0][2] + red[0][3];
    partial[256 + blockIdx.x] = red[1][0] + red[1][1] + red[1][2] + red[1][3];
  }
}

// ---------------- Kernel 1b: finalize stats (1 block) ----------------
__global__ __launch_bounds__(64) void gn_final_kernel(const float* __restrict__ partial,
                                                      float* __restrict__ stats) {
  int bg = threadIdx.x;
  if (bg < 32) {
    float S = 0.f, SS = 0.f;
#pragma unroll
    for (int sp = 0; sp < 8; ++sp) {
      S += partial[bg * 8 + sp];
      SS += partial[256 + bg * 8 + sp];
    }
    const float invN = 1.0f / 131072.0f;
    float mean = S * invN;
    float var = SS * invN - mean * mean;
    stats[bg] = mean;
    stats[32 + bg] = rsqrtf(var + 1e-5f);
  }
}

// ---------------- Kernel 2: normalize + transpose -> h_t[b][s][c] (bf16) ----------------
__global__ __launch_bounds__(256) void norm_t_kernel(const float* __restrict__ x,
                                                     const float* __restrict__ nw,
                                                     const float* __restrict__ nb,
                                                     const float* __restrict__ stats,
                                                     u16* __restrict__ h_t) {
  int b = blockIdx.y;
  int s = blockIdx.x * 64 + (threadIdx.x & 63);
  int w = threadIdx.x >> 6;
  const float* xb = x + (size_t)b * CC * HW;
  u16* hb = h_t + ((size_t)b * HW + s) * CC;
#pragma unroll
  for (int cc = 0; cc < 8; ++cc) {
    int c0 = w * 64 + cc * 8;
    union { u16 u[8]; uint4 v; } pk;
#pragma unroll
    for (int j = 0; j < 8; ++j) {
      int c = c0 + j;
      int g = c >> 5;
      float mean = stats[b * 8 + g];
      float rstd = stats[32 + b * 8 + g];
      float a = nw[c] * rstd;
      float bb2 = nb[c] - mean * a;
      float vv = xb[(size_t)c * HW + s];
      pk.u[j] = f2bf(vv * a + bb2);
    }
    *(uint4*)(hb + c0) = pk.v;
  }
}

// ---------------- Kernel 3: qk GEMM -> q_t[b][h][s][c] ; K in FRAGMENT-MAJOR ----
// K layout: kf[bh][jb32][kc][lane][8] with lane = hi*32 + ql:
//   element = K[jb32*32 + ql][kc*16 + hi*8 + j]
__global__ __launch_bounds__(256) void gemm_qk_kernel(const u16* __restrict__ h_t,
                                                      const u16* __restrict__ wbf,
                                                      const float* __restrict__ qb,
                                                      u16* __restrict__ q_t,
                                                      u16* __restrict__ k_f) {
  int b = blockIdx.z;
  int lane = threadIdx.x & 63, wave = threadIdx.x >> 6;
  int lr = lane & 15, lg = lane >> 4;
  int m0 = blockIdx.x * 128 + (wave >> 1) * 64;  // s
  int n0 = blockIdx.y * 128 + (wave & 1) * 64;   // o (0..512)
  const u16* hb = h_t + (size_t)b * HW * CC;
  f32x4 acc[4][4] = {};
  for (int kc = 0; kc < 8; ++kc) {
    int ko = kc * 32 + lg * 8;
    bf16x8 af[4], bfr[4];
#pragma unroll
    for (int mi = 0; mi < 4; ++mi)
      af[mi] = *(const bf16x8*)(hb + (size_t)(m0 + mi * 16 + lr) * CC + ko);
#pragma unroll
    for (int ni = 0; ni < 4; ++ni)
      bfr[ni] = *(const bf16x8*)(wbf + (size_t)(n0 + ni * 16 + lr) * CC + ko);
#pragma unroll
    for (int mi = 0; mi < 4; ++mi)
#pragma unroll
      for (int ni = 0; ni < 4; ++ni)
        acc[mi][ni] = MFMA16(af[mi], bfr[ni], acc[mi][ni]);
  }
  bool isq = (blockIdx.y < 2);
  if (isq) {
#pragma unroll
    for (int ni = 0; ni < 4; ++ni) {
      int o = n0 + ni * 16 + lr;
      float bias = qb[o];
      u16* dp = q_t + (((size_t)b * NH + (o >> 6)) * HW) * HD + (o & 63);
#pragma unroll
      for (int mi = 0; mi < 4; ++mi)
#pragma unroll
        for (int r = 0; r < 4; ++r) {
          int s = m0 + mi * 16 + lg * 4 + r;
          dp[(size_t)s * HD] = f2bf((acc[mi][ni][r] + bias) * QSCALE);
        }
    }
  } else {
#pragma unroll
    for (int ni = 0; ni < 4; ++ni) {
      int o = n0 + ni * 16 + lr;
      int oc = o - 256;
      int h = oc >> 6, c = oc & 63;
      int kc = c >> 4, hi2 = (c >> 3) & 1, j = c & 7;
      float bias = qb[o];
      u16* base = k_f + (size_t)(b * NH + h) * HW * HD;
#pragma unroll
      for (int mi = 0; mi < 4; ++mi)
#pragma unroll
        for (int r = 0; r < 4; ++r) {
          int s = m0 + mi * 16 + lg * 4 + r;
          int jb32 = s >> 5, ql2 = s & 31;
          base[((size_t)(jb32 * 4 + kc) * 64 + hi2 * 32 + ql2) * 8 + j] =
              f2bf(acc[mi][ni][r] + bias);
        }
    }
  }
}

// ---------------- Kernel 4: v GEMM -> V in FRAGMENT-MAJOR ----------------
// V layout: vf[bh][jb64][half][kc][lane][8] with lane = hi*32 + ql:
//   element = V[half*32 + ql][jb64*64 + kc*16 + hi*8 + j]   (V = [c][kv])
__global__ __launch_bounds__(256) void gemm_v_kernel(const u16* __restrict__ h_t,
                                                     const u16* __restrict__ wbf,
                                                     const float* __restrict__ qb,
                                                     u16* __restrict__ v_f) {
  int b = blockIdx.z;
  int lane = threadIdx.x & 63, wave = threadIdx.x >> 6;
  int lr = lane & 15, lg = lane >> 4;
  int m0 = blockIdx.y * 128 + (wave >> 1) * 64;  // o (0..255) = channel dim
  int n0 = blockIdx.x * 128 + (wave & 1) * 64;   // s = kv dim
  const u16* hb = h_t + (size_t)b * HW * CC;
  f32x4 acc[4][4] = {};
  for (int kc = 0; kc < 8; ++kc) {
    int ko = kc * 32 + lg * 8;
    bf16x8 af[4], bfr[4];
#pragma unroll
    for (int mi = 0; mi < 4; ++mi)
      af[mi] = *(const bf16x8*)(wbf + (size_t)(512 + m0 + mi * 16 + lr) * CC + ko);
#pragma unroll
    for (int ni = 0; ni < 4; ++ni)
      bfr[ni] = *(const bf16x8*)(hb + (size_t)(n0 + ni * 16 + lr) * CC + ko);
#pragma unroll
    for (int mi = 0; mi < 4; ++mi)
#pragma unroll
      for (int ni = 0; ni < 4; ++ni)
        acc[mi][ni] = MFMA16(af[mi], bfr[ni], acc[mi][ni]);
  }
#pragma unroll
  for (int mi = 0; mi < 4; ++mi)
#pragma unroll
    for (int r = 0; r < 4; ++r) {
      int o = m0 + mi * 16 + lg * 4 + r;
      int h = o >> 6, c = o & 63;
      int half = c >> 5, qlc = c & 31;
      float bias = qb[512 + o];
      u16* base = v_f + (size_t)(b * NH + h) * HW * HD;
#pragma unroll
      for (int ni = 0; ni < 4; ++ni) {
        int s = n0 + ni * 16 + lr;
        int jb64 = s >> 6, w = s & 63;
        int kc = w >> 4, hi2 = (w >> 3) & 1, j = w & 7;
        base[((size_t)((jb64 * 2 + half) * 4 + kc) * 64 + hi2 * 32 + qlc) * 8 + j] =
            f2bf(acc[mi][ni][r] + bias);
      }
    }
}

// ---------------- Kernel 5: flash attention, LDS-free + split-KV x2 ----------------
// 512 threads = 8 free-running waves (no barriers in loop). Waves 0-3 process
// even KV tiles, 4-7 odd tiles, same 128 q-rows. Fixed-reference softmax makes
// the merge a PLAIN ADD of (O, l). 33.8KB LDS (merge only) -> 4 blocks/CU
// -> 4 waves/SIMD. K/V fragment loads: coalesced 1KB dwordx4 from frag-major.
__global__ __launch_bounds__(512) void attn_kernel(const u16* __restrict__ q_t,
                                                   const u16* __restrict__ k_f,
                                                   const u16* __restrict__ v_f,
                                                   u16* __restrict__ o_t) {
  __shared__ float mbuf[4 * 33 * 64];   // [wsub][of0(16)|of1(16)|l(1)][lane]
  int bh = blockIdx.y;
  int tid = threadIdx.x;
  int wave = tid >> 6, lane = tid & 63;
  int half = wave >> 2, wsub = wave & 3;
  int ql = lane & 31, hi = lane >> 5;
  int q0w = blockIdx.x * 128 + wsub * 32;
  const u16* qp = q_t + (size_t)bh * HW * HD;
  const u16* kfb = k_f + (size_t)bh * HW * HD + lane * 8;
  const u16* vfb = v_f + (size_t)bh * HW * HD + lane * 8;

  // Q B-fragments (B[k=c][n=q])
  bf16x8 qf[4];
#pragma unroll
  for (int kc = 0; kc < 4; ++kc)
    qf[kc] = *(const bf16x8*)(qp + (size_t)(q0w + ql) * HD + kc * 16 + hi * 8);

  float l_run = 0.f;
  f32x16 of0 = {}, of1 = {};
  bf16x8 kfr[8], vfr[8];

  // prologue: K(half) fragments
  {
    const u16* kb = kfb + (size_t)half * 8 * 512;
#pragma unroll
    for (int kc = 0; kc < 4; ++kc) {
      kfr[kc] = *(const bf16x8*)(kb + (size_t)kc * 512);
      kfr[4 + kc] = *(const bf16x8*)(kb + (size_t)(4 + kc) * 512);
    }
  }

#pragma unroll 1
  for (int it = half; it < 64; it += 2) {
    // V(it) fragment loads — consumed at PV after exp2+pack
    const u16* vb = vfb + (size_t)it * 8 * 512;
#pragma unroll
    for (int kc = 0; kc < 4; ++kc) {
      vfr[kc] = *(const bf16x8*)(vb + (size_t)kc * 512);            // half 0
      vfr[4 + kc] = *(const bf16x8*)(vb + (size_t)(4 + kc) * 512);  // half 1
    }

    // QK(it): S[kv][q] = K·Q  (scale+log2e folded into q)
    f32x16 s0 = {}, s1 = {};
    __builtin_amdgcn_s_setprio(1);
#pragma unroll
    for (int kc = 0; kc < 4; ++kc) {
      s0 = MFMA32(kfr[kc], qf[kc], s0);
      s1 = MFMA32(kfr[4 + kc], qf[kc], s1);
    }
    __builtin_amdgcn_s_setprio(0);

    // K(it+2) fragment loads (WAR on kfr safe: MFMA reads at issue)
    if (it < 62) {
      const u16* kb = kfb + (size_t)(it + 2) * 8 * 512;
#pragma unroll
      for (int kc = 0; kc < 4; ++kc) {
        kfr[kc] = *(const bf16x8*)(kb + (size_t)kc * 512);
        kfr[4 + kc] = *(const bf16x8*)(kb + (size_t)(4 + kc) * 512);
      }
    }

    // P = exp2(S) directly — fixed reference (no max tracking)
#pragma unroll
    for (int i = 0; i < 16; ++i) {
      s0[i] = __builtin_amdgcn_exp2f(s0[i]);
      s1[i] = __builtin_amdgcn_exp2f(s1[i]);
    }

    // pf(it) = P -> bf16 B-fragments via cvt_pk + permlane32_swap
    bf16x8 pf[4];
#pragma unroll
    for (int kc = 0; kc < 4; ++kc) {
      const f32x16 pv = (kc < 2) ? s0 : s1;
      const int b8 = (kc & 1) * 8;
      unsigned A0 = cvtpk(pv[b8 + 0], pv[b8 + 1]);
      unsigned A1 = cvtpk(pv[b8 + 2], pv[b8 + 3]);
      unsigned B0 = cvtpk(pv[b8 + 4], pv[b8 + 5]);
      unsigned B1 = cvtpk(pv[b8 + 6], pv[b8 + 7]);
      i32x2 r0 = __builtin_amdgcn_permlane32_swap((int)A0, (int)B0, false, false);
      i32x2 r1 = __builtin_amdgcn_permlane32_swap((int)A1, (int)B1, false, false);
      union { unsigned w[4]; bf16x8 v8; } u;
      u.w[0] = (unsigned)r0[0]; u.w[1] = (unsigned)r1[0];
      u.w[2] = (unsigned)r0[1]; u.w[3] = (unsigned)r1[1];
      pf[kc] = u.v8;
    }

    // PV(it): O^T[c][q] += V^T · P^T
    __builtin_amdgcn_s_setprio(1);
#pragma unroll
    for (int kc = 0; kc < 4; ++kc) {
      of0 = MFMA32(vfr[kc], pf[kc], of0);
      of1 = MFMA32(vfr[4 + kc], pf[kc], of1);
    }
    __builtin_amdgcn_s_setprio(0);

    // l-sum AFTER PV issue (off the critical path)
    float t8[8];
#pragma unroll
    for (int i = 0; i < 8; ++i)
      t8[i] = (s0[i] + s0[i + 8]) + (s1[i] + s1[i + 8]);
    float t4a = t8[0] + t8[4], t4b = t8[1] + t8[5];
    float t4c = t8[2] + t8[6], t4d = t8[3] + t8[7];
    l_run += (t4a + t4b) + (t4c + t4d);
  }

  // ---- merge the two KV-halves: fixed reference -> plain ADD ----
  __syncthreads();
  if (half == 1) {
    float* mb = mbuf + (size_t)wsub * 33 * 64 + lane;
#pragma unroll
    for (int i = 0; i < 16; ++i) mb[i * 64] = of0[i];
#pragma unroll
    for (int i = 0; i < 16; ++i) mb[(16 + i) * 64] = of1[i];
    mb[32 * 64] = l_run;
  }
  __syncthreads();
  if (half == 0) {
    const float* mb = mbuf + (size_t)wsub * 33 * 64 + lane;
#pragma unroll
    for (int i = 0; i < 16; ++i) of0[i] += mb[i * 64];
#pragma unroll
    for (int i = 0; i < 16; ++i) of1[i] += mb[(16 + i) * 64];
    l_run += mb[32 * 64];
    float l_tot = l_run + __shfl_xor(l_run, 32);
    float inv_l = 1.0f / l_tot;
    int bb = bh >> 2, hh = bh & 3;
    u16* orow = o_t + ((size_t)bb * HW + q0w + ql) * CC + hh * 64;
#pragma unroll
    for (int cb = 0; cb < 2; ++cb) {
      const f32x16 o = cb ? of1 : of0;
#pragma unroll
      for (int t = 0; t < 4; ++t) {
        int c0 = cb * 32 + t * 8 + hi * 4;
        union { u16 u[4]; uint2 w; } pk;
#pragma unroll
        for (int r = 0; r < 4; ++r) pk.u[r] = f2bf(o[t * 4 + r] * inv_l);
        *(uint2*)(orow + c0) = pk.w;
      }
    }
  }
}

// ---------------- Kernel 6: proj GEMM + bias + residual (fp32 out) ----------------
__global__ __launch_bounds__(256) void proj_kernel(const u16* __restrict__ o_t,
                                                   const u16* __restrict__ wbf,
                                                   const float* __restrict__ pb,
                                                   const float* __restrict__ x,
                                                   float* __restrict__ out) {
  int b = blockIdx.z;
  int lane = threadIdx.x & 63, wave = threadIdx.x >> 6;
  int lr = lane & 15, lg = lane >> 4;
  int m0 = blockIdx.x * 128 + (wave >> 1) * 64;  // s
  int n0 = blockIdx.y * 128 + (wave & 1) * 64;   // o (0..255)
  const u16* ob = o_t + (size_t)b * HW * CC;
  const u16* pwbf = wbf + (size_t)768 * CC;
  f32x4 acc[4][4] = {};
  for (int kc = 0; kc < 8; ++kc) {
    int ko = kc * 32 + lg * 8;
    bf16x8 af[4], bfr[4];
#pragma unroll
    for (int mi = 0; mi < 4; ++mi)
      af[mi] = *(const bf16x8*)(ob + (size_t)(m0 + mi * 16 + lr) * CC + ko);
#pragma unroll
    for (int ni = 0; ni < 4; ++ni)
      bfr[ni] = *(const bf16x8*)(pwbf + (size_t)(n0 + ni * 16 + lr) * CC + ko);
#pragma unroll
    for (int mi = 0; mi < 4; ++mi)
#pragma unroll
      for (int ni = 0; ni < 4; ++ni)
        acc[mi][ni] = MFMA16(af[mi], bfr[ni], acc[mi][ni]);
  }
#pragma unroll
  for (int ni = 0; ni < 4; ++ni) {
    int o = n0 + ni * 16 + lr;
    float bias = pb[o];
    const float* xp = x + ((size_t)b * CC + o) * HW;
    float* op = out + ((size_t)b * CC + o) * HW;
#pragma unroll
    for (int mi = 0; mi < 4; ++mi) {
      int sb = m0 + mi * 16 + lg * 4;
      float4 xv = *(const float4*)(xp + sb);
      float4 res;
      res.x = acc[mi][ni][0] + bias + xv.x;
      res.y = acc[mi][ni][1] + bias + xv.y;
      res.z = acc[mi][ni][2] + bias + xv.z;
      res.w = acc[mi][ni][3] + bias + xv.w;
      *(float4*)(op + sb) = res;
    }
  }
}

extern "C" void kernel_launch(void* const* d_in, const int* in_sizes, int n_in,
                              void* d_out, int out_size, void* d_ws, size_t ws_size,
                              hipStream_t stream) {
  const float* x = (const float*)d_in[0];
  const float* nw = (const float*)d_in[1];
  const float* nb = (const float*)d_in[2];
  const float* qw = (const float*)d_in[3];
  const float* qb = (const float*)d_in[4];
  const float* pw = (const float*)d_in[5];
  const float* pb = (const float*)d_in[6];
  float* out = (float*)d_out;

  // workspace layout (o_t aliases h_t: h_t dead after gemm_v)
  float* stats = (float*)d_ws;                       // 64 floats
  float* partial = stats + 64;                       // 512 floats
  u16* h_t = (u16*)((char*)d_ws + 4096);             // [B][HW][C]      8 MB
  u16* q_t = h_t + (size_t)BB * HW * CC;             // [B][NH][HW][HD] 8 MB
  u16* k_f = q_t + (size_t)BB * HW * CC;             // fragment-major  8 MB
  u16* v_f = k_f + (size_t)BB * HW * CC;             // fragment-major  8 MB
  u16* wbf = v_f + (size_t)BB * HW * CC;             // (768+256)*256   512 KB
  u16* o_t = h_t;                                    // reuse

  gn_partial_kernel<<<256, 256, 0, stream>>>(x, partial);
  gn_final_kernel<<<1, 64, 0, stream>>>(partial, stats);
  w2bf_kernel<<<256, 256, 0, stream>>>(qw, pw, wbf);
  norm_t_kernel<<<dim3(HW / 64, BB), 256, 0, stream>>>(x, nw, nb, stats, h_t);
  gemm_qk_kernel<<<dim3(HW / 128, 4, BB), 256, 0, stream>>>(h_t, wbf, qb, q_t, k_f);
  gemm_v_kernel<<<dim3(HW / 128, 2, BB), 256, 0, stream>>>(h_t, wbf, qb, v_f);
  attn_kernel<<<dim3(HW / 128, BB * NH), 512, 0, stream>>>(q_t, k_f, v_f, o_t);
  proj_kernel<<<dim3(HW / 128, 2, BB), 256, 0, stream>>>(o_t, wbf, pb, x, out);
}